// Round 2
// baseline (7861.511 us; speedup 1.0000x reference)
//
#include <hip/hip_runtime.h>
#include <hip/hip_bf16.h>

typedef __bf16 bf8 __attribute__((ext_vector_type(8)));   // 16 B
typedef float  f32x4 __attribute__((ext_vector_type(4)));

#define TT 512
#define BBATCH 64
#define IDIM 1024
#define HDIM 1024
#define G4 4096

__device__ __forceinline__ float sigf(float x) {
  x = fminf(fmaxf(x, -30.f), 30.f);
  return 1.f / (1.f + __expf(-x));
}
__device__ __forceinline__ float tanh_(float x) {
  x = fminf(fmaxf(x, -15.f), 15.f);
  float e = __expf(2.f * x);
  return (e - 1.f) / (e + 1.f);
}
__device__ __forceinline__ f32x4 MFMA(bf8 a, bf8 b, f32x4 c) {
  return __builtin_amdgcn_mfma_f32_16x16x32_bf16(a, b, c, 0, 0, 0);
}
__device__ __forceinline__ void gload_lds16(const void* g, void* l) {
  __builtin_amdgcn_global_load_lds(
      (const __attribute__((address_space(1))) unsigned int*)g,
      (__attribute__((address_space(3))) unsigned int*)l, 16, 0, 0);
}

// ---------------------------------------------------------------------------
// Weight transpose+convert via LDS tiles.
// z<4: WxT_sw[n][k] (bf16, 16B-granule swizzled: q_phys = q_log ^ ((n>>1)&3))
// z>=4: WhT[n][k] plain bf16.   n = gate*1024 + j.
// ---------------------------------------------------------------------------
__global__ __launch_bounds__(256) void k_convw(
    const float* __restrict__ s0, const float* __restrict__ s1,
    const float* __restrict__ s2, const float* __restrict__ s3,
    const float* __restrict__ s4, const float* __restrict__ s5,
    const float* __restrict__ s6, const float* __restrict__ s7,
    __bf16* __restrict__ WxT, __bf16* __restrict__ WhT) {
  int z = blockIdx.z;
  const float* src = (z == 0) ? s0 : (z == 1) ? s1 : (z == 2) ? s2 :
                     (z == 3) ? s3 : (z == 4) ? s4 : (z == 5) ? s5 :
                     (z == 6) ? s6 : s7;
  int j0 = blockIdx.x * 64, k0 = blockIdx.y * 64;
  __shared__ float T[64][65];
  int tid = threadIdx.x;
#pragma unroll
  for (int i = 0; i < 16; ++i) {
    int idx = tid + i * 256;
    int kl = idx >> 6, jl = idx & 63;
    T[kl][jl] = src[(size_t)(k0 + kl) * 1024 + j0 + jl];
  }
  __syncthreads();
#pragma unroll
  for (int i = 0; i < 2; ++i) {
    int Gt = tid + i * 256;            // 0..511
    int nl = Gt >> 3, gq = Gt & 7;     // n-local, granule-in-64k
    int n = (z & 3) * 1024 + j0 + nl;
    bf8 v;
#pragma unroll
    for (int e = 0; e < 8; ++e) v[e] = (__bf16)T[gq * 8 + e][nl];
    if (z < 4) {
      int qp = (gq & 3) ^ ((nl >> 1) & 3);
      *(bf8*)&WxT[(size_t)n * 1024 + k0 + (gq >> 2) * 32 + qp * 8] = v;
    } else {
      *(bf8*)&WhT[(size_t)n * 1024 + k0 + gq * 8] = v;
    }
  }
}

__global__ void k_bias(const float* __restrict__ b0, const float* __restrict__ b1,
                       const float* __restrict__ b2, const float* __restrict__ b3,
                       float* __restrict__ bias) {
  int i = blockIdx.x * 256 + threadIdx.x;
  if (i < G4) {
    const float* s = (i < 1024) ? b0 : (i < 2048) ? b1 : (i < 3072) ? b2 : b3;
    bias[i] = s[i & 1023];
  }
}

// ---------------------------------------------------------------------------
// X chunk convert fp32 -> bf16, same granule swizzle as WxT (rows = m).
// ---------------------------------------------------------------------------
__global__ void k_convx(const float* __restrict__ X, __bf16* __restrict__ Xb,
                        int nGran) {
  int gid = blockIdx.x * 256 + threadIdx.x;
  if (gid >= nGran) return;
  int m = gid >> 7, G = gid & 127;
  const float4* s = (const float4*)(X + ((size_t)m * 1024 + G * 8));
  float4 u = s[0], v2 = s[1];
  bf8 o;
  o[0]=(__bf16)u.x; o[1]=(__bf16)u.y; o[2]=(__bf16)u.z; o[3]=(__bf16)u.w;
  o[4]=(__bf16)v2.x; o[5]=(__bf16)v2.y; o[6]=(__bf16)v2.z; o[7]=(__bf16)v2.w;
  int qp = (G & 3) ^ ((m >> 1) & 3);
  *(bf8*)&Xb[(size_t)m * 1024 + (G >> 2) * 32 + qp * 8] = o;
}

// ---------------------------------------------------------------------------
// Phase 1 GEMM: C[m][n] = sum_k A_sw[m][k]*B_sw[n][k] + bias[n]
// 128x128 tile, BK=32, global_load_lds width-16, swizzled (conflict-free).
// ---------------------------------------------------------------------------
__global__ __launch_bounds__(256) void k_gemm(const __bf16* __restrict__ A,
                                              const __bf16* __restrict__ B,
                                              const float* __restrict__ bias,
                                              float* __restrict__ C, int M) {
  __shared__ bf8 As[512];  // [128 rows][4 granules] = 8KB
  __shared__ bf8 Bs[512];
  int tid = threadIdx.x, lane = tid & 63, w = tid >> 6;
  int m0 = blockIdx.y * 128, n0 = blockIdx.x * 128;
  int wr = (w >> 1) * 64, wc = (w & 1) * 64;
  int lr = lane >> 2, lq = lane & 3;

  f32x4 acc[4][4] = {};

  int ra0 = m0 + w * 16 + lr;      if (ra0 > M - 1) ra0 = M - 1;
  int ra1 = m0 + 64 + w * 16 + lr; if (ra1 > M - 1) ra1 = M - 1;
  const __bf16* a0p = A + (size_t)ra0 * 1024 + lq * 8;
  const __bf16* a1p = A + (size_t)ra1 * 1024 + lq * 8;
  const __bf16* b0p = B + (size_t)(n0 + w * 16 + lr) * 1024 + lq * 8;
  const __bf16* b1p = B + (size_t)(n0 + 64 + w * 16 + lr) * 1024 + lq * 8;
  bf8* asl0 = &As[(w * 16) * 4];      bf8* asl1 = &As[(64 + w * 16) * 4];
  bf8* bsl0 = &Bs[(w * 16) * 4];      bf8* bsl1 = &Bs[(64 + w * 16) * 4];

  int r16 = lane & 15, q = lane >> 4;

  for (int kt = 0; kt < 32; ++kt) {
    __syncthreads();
    gload_lds16(a0p + kt * 32, asl0);
    gload_lds16(a1p + kt * 32, asl1);
    gload_lds16(b0p + kt * 32, bsl0);
    gload_lds16(b1p + kt * 32, bsl1);
    __syncthreads();
    bf8 af[4], bfv[4];
#pragma unroll
    for (int r = 0; r < 4; ++r) {
      int rr = wr + r * 16 + r16;
      af[r] = *(const bf8*)((const char*)As + rr * 64 + ((q ^ ((rr >> 1) & 3)) * 16));
    }
#pragma unroll
    for (int c = 0; c < 4; ++c) {
      int rr = wc + c * 16 + r16;
      bfv[c] = *(const bf8*)((const char*)Bs + rr * 64 + ((q ^ ((rr >> 1) & 3)) * 16));
    }
#pragma unroll
    for (int r = 0; r < 4; ++r)
#pragma unroll
      for (int c = 0; c < 4; ++c)
        acc[r][c] = MFMA(af[r], bfv[c], acc[r][c]);
  }

  int cj = lane & 15, hi4 = (lane >> 4) * 4;
#pragma unroll
  for (int c = 0; c < 4; ++c) {
    int col = n0 + wc + c * 16 + cj;
    float bc = bias[col];
#pragma unroll
    for (int r = 0; r < 4; ++r) {
#pragma unroll
      for (int qq = 0; qq < 4; ++qq) {
        int rr = wr + r * 16 + hi4 + qq;
        if (m0 + rr < M) C[(size_t)(m0 + rr) * G4 + col] = acc[r][c][qq] + bc;
      }
    }
  }
}

// ---------------------------------------------------------------------------
// Persistent recurrence: one launch per chunk of Tc steps.
// 256 blocks x 256 thr. block = (mb = bid&3: 16 batches) x (hc = bid>>2: 16 h-cols).
// wave w = gate. Wh frags in registers (full K). 4 sub-grid barriers (per mb).
// ---------------------------------------------------------------------------
__global__ __launch_bounds__(256) void k_recur(
    const float* __restrict__ Xg, const __bf16* __restrict__ WhT,
    __bf16* __restrict__ hb0, __bf16* __restrict__ hb1,
    float* __restrict__ S, float* __restrict__ out,
    int* __restrict__ bar, int t0, int Tc) {
  __shared__ bf8 As[2048];           // 16 rows x 128 granules, swizzled, 32KB
  __shared__ float Gs[4][16][17];
  int tid = threadIdx.x, lane = tid & 63, w = tid >> 6;
  int mb = blockIdx.x & 3, hc = blockIdx.x >> 2;
  int* cnt = bar + mb * 32;

  // Wh fragments: cols n = w*1024 + hc*16 + (lane&15), all K. 32 x bf8.
  int ncol = w * 1024 + hc * 16 + (lane & 15);
  const __bf16* wrow = WhT + (size_t)ncol * 1024 + (lane >> 4) * 8;
  bf8 Bf[32];
#pragma unroll
  for (int kk = 0; kk < 32; ++kk) Bf[kk] = *(const bf8*)(wrow + kk * 32);

  int r = lane & 15, q = lane >> 4, rx = r & 7;
  const char* abase = (const char*)As + r * 2048;

  for (int lt = 0; lt < Tc; ++lt) {
    int t = t0 + lt;
    f32x4 acc = {};
    if (t > 0) {
      const __bf16* hp = ((t - 1) & 1) ? hb1 : hb0;
      const __bf16* src = hp + mb * 16 * 1024;
#pragma unroll
      for (int i = 0; i < 8; ++i) {
        int g = tid + i * 256;               // granule 0..2047
        int rr = g >> 7, G = g & 127;
        bf8 v = *(const bf8*)(src + g * 8);
        *(bf8*)((char*)As + rr * 2048 + ((G ^ (rr & 7)) * 16)) = v;
      }
      __syncthreads();
      f32x4 a0 = {}, a1 = {}, a2 = {}, a3 = {};
#pragma unroll
      for (int kk = 0; kk < 32; kk += 4) {
        bf8 f0 = *(const bf8*)(abase + ((((kk + 0) * 4 + q) ^ rx) * 16));
        bf8 f1 = *(const bf8*)(abase + ((((kk + 1) * 4 + q) ^ rx) * 16));
        bf8 f2 = *(const bf8*)(abase + ((((kk + 2) * 4 + q) ^ rx) * 16));
        bf8 f3 = *(const bf8*)(abase + ((((kk + 3) * 4 + q) ^ rx) * 16));
        a0 = MFMA(f0, Bf[kk + 0], a0);
        a1 = MFMA(f1, Bf[kk + 1], a1);
        a2 = MFMA(f2, Bf[kk + 2], a2);
        a3 = MFMA(f3, Bf[kk + 3], a3);
      }
      acc = (a0 + a1) + (a2 + a3);
    }
    // exchange gate pre-activations
    int cc = lane & 15, rr4 = (lane >> 4) * 4;
    Gs[w][rr4 + 0][cc] = acc[0];
    Gs[w][rr4 + 1][cc] = acc[1];
    Gs[w][rr4 + 2][cc] = acc[2];
    Gs[w][rr4 + 3][cc] = acc[3];
    __syncthreads();
    // gates + state
    int b_loc = tid >> 4, hcl = tid & 15;
    int brow = mb * 16 + b_loc, hcol = hc * 16 + hcl;
    const float* xr = Xg + ((size_t)lt * 64 + brow) * G4;
    float ga = Gs[0][b_loc][hcl] + xr[0 * 1024 + hcol];
    float gi = Gs[1][b_loc][hcl] + xr[1 * 1024 + hcol];
    float gf = Gs[2][b_loc][hcl] + xr[2 * 1024 + hcol];
    float go = Gs[3][b_loc][hcl] + xr[3 * 1024 + hcol];
    float a_ = tanh_(ga), i_ = sigf(gi), f_ = sigf(gf), o_ = sigf(go);
    float s_old = (t == 0) ? 0.f : S[brow * 1024 + hcol];
    float s_new = a_ * i_ + s_old * f_;
    float h = tanh_(s_new) * o_;
    S[brow * 1024 + hcol] = s_new;
    out[((size_t)t * 64 + brow) * 1024 + hcol] = h;
    __bf16* hn = (t & 1) ? hb1 : hb0;
    hn[brow * 1024 + hcol] = (__bf16)h;

    if (lt < Tc - 1) {
      __syncthreads();   // all stores issued & LDS reads done
      if (tid == 0) {
        __hip_atomic_fetch_add(cnt, 1, __ATOMIC_ACQ_REL, __HIP_MEMORY_SCOPE_AGENT);
        int target = 64 * (lt + 1);
        while (__hip_atomic_load(cnt, __ATOMIC_ACQUIRE, __HIP_MEMORY_SCOPE_AGENT) < target)
          __builtin_amdgcn_s_sleep(2);
      }
      __syncthreads();
    }
  }
}

// ---------------------------------------------------------------------------
extern "C" void kernel_launch(void* const* d_in, const int* in_sizes, int n_in,
                              void* d_out, int out_size, void* d_ws, size_t ws_size,
                              hipStream_t stream) {
  const float* X  = (const float*)d_in[0];
  const float* wa = (const float*)d_in[1];
  const float* wi = (const float*)d_in[2];
  const float* wf = (const float*)d_in[3];
  const float* wo = (const float*)d_in[4];
  const float* ha = (const float*)d_in[5];
  const float* hi = (const float*)d_in[6];
  const float* hf = (const float*)d_in[7];
  const float* ho = (const float*)d_in[8];
  const float* b0 = (const float*)d_in[9];
  const float* b1 = (const float*)d_in[10];
  const float* b2 = (const float*)d_in[11];
  const float* b3 = (const float*)d_in[12];
  float* out = (float*)d_out;
  char* ws = (char*)d_ws;

  size_t off = 0;
  auto alloc = [&](size_t bytes) {
    void* p = ws + off;
    off += (bytes + 255) & ~(size_t)255;
    return p;
  };
  __bf16* WxT = (__bf16*)alloc((size_t)G4 * IDIM * 2);
  __bf16* WhT = (__bf16*)alloc((size_t)G4 * HDIM * 2);
  float* bias = (float*)alloc(G4 * 4);
  float* S    = (float*)alloc((size_t)BBATCH * HDIM * 4);
  __bf16* hb0 = (__bf16*)alloc((size_t)BBATCH * HDIM * 2);
  __bf16* hb1 = (__bf16*)alloc((size_t)BBATCH * HDIM * 2);
  int* bar    = (int*)alloc(4096);
  size_t base = off;

  const size_t perT = (size_t)BBATCH * G4 * 4 + (size_t)BBATCH * IDIM * 2;
  int Tc = 64;
  while (Tc > 1 && base + (size_t)Tc * perT > ws_size) Tc >>= 1;
  float* Xg   = (float*)(ws + base);
  __bf16* Xbf = (__bf16*)(ws + base + (size_t)Tc * BBATCH * G4 * 4);

  k_convw<<<dim3(16, 16, 8), dim3(256), 0, stream>>>(wa, wi, wf, wo, ha, hi, hf,
                                                     ho, WxT, WhT);
  k_bias<<<dim3(16), dim3(256), 0, stream>>>(b0, b1, b2, b3, bias);

  for (int t0 = 0; t0 < TT; t0 += Tc) {
    int M = Tc * BBATCH;
    int nGran = M * 128;
    k_convx<<<dim3((nGran + 255) / 256), dim3(256), 0, stream>>>(
        X + (size_t)t0 * BBATCH * IDIM, Xbf, nGran);
    dim3 g1(G4 / 128, (M + 127) / 128);
    k_gemm<<<g1, dim3(256), 0, stream>>>(Xbf, WxT, bias, Xg, M);
    hipMemsetAsync(bar, 0, 4096, stream);
    k_recur<<<dim3(256), dim3(256), 0, stream>>>(Xg, WhT, hb0, hb1, S, out, bar,
                                                 t0, Tc);
  }
}

// Round 3
// 5099.590 us; speedup vs baseline: 1.5416x; 1.5416x over previous
//
#include <hip/hip_runtime.h>
#include <hip/hip_bf16.h>

typedef __bf16 bf8 __attribute__((ext_vector_type(8)));   // 16 B
typedef float  f32x4 __attribute__((ext_vector_type(4)));

#define TT 512
#define BBATCH 64
#define IDIM 1024
#define HDIM 1024
#define G4 4096

__device__ __forceinline__ float sigf(float x) {
  x = fminf(fmaxf(x, -30.f), 30.f);
  return 1.f / (1.f + __expf(-x));
}
__device__ __forceinline__ float tanh_(float x) {
  x = fminf(fmaxf(x, -15.f), 15.f);
  float e = __expf(2.f * x);
  return (e - 1.f) / (e + 1.f);
}
__device__ __forceinline__ f32x4 MFMA(bf8 a, bf8 b, f32x4 c) {
  return __builtin_amdgcn_mfma_f32_16x16x32_bf16(a, b, c, 0, 0, 0);
}
__device__ __forceinline__ void gload_lds16(const void* g, void* l) {
  __builtin_amdgcn_global_load_lds(
      (const __attribute__((address_space(1))) unsigned int*)g,
      (__attribute__((address_space(3))) unsigned int*)l, 16, 0, 0);
}

// ---------------------------------------------------------------------------
// Weight transpose+convert via LDS tiles. (unchanged, proven)
// z<4: WxT_sw[n][k] (bf16, 16B-granule swizzled: q_phys = q_log ^ ((n>>1)&3))
// z>=4: WhT[n][k] plain bf16.   n = gate*1024 + j.
// ---------------------------------------------------------------------------
__global__ __launch_bounds__(256) void k_convw(
    const float* __restrict__ s0, const float* __restrict__ s1,
    const float* __restrict__ s2, const float* __restrict__ s3,
    const float* __restrict__ s4, const float* __restrict__ s5,
    const float* __restrict__ s6, const float* __restrict__ s7,
    __bf16* __restrict__ WxT, __bf16* __restrict__ WhT) {
  int z = blockIdx.z;
  const float* src = (z == 0) ? s0 : (z == 1) ? s1 : (z == 2) ? s2 :
                     (z == 3) ? s3 : (z == 4) ? s4 : (z == 5) ? s5 :
                     (z == 6) ? s6 : s7;
  int j0 = blockIdx.x * 64, k0 = blockIdx.y * 64;
  __shared__ float T[64][65];
  int tid = threadIdx.x;
#pragma unroll
  for (int i = 0; i < 16; ++i) {
    int idx = tid + i * 256;
    int kl = idx >> 6, jl = idx & 63;
    T[kl][jl] = src[(size_t)(k0 + kl) * 1024 + j0 + jl];
  }
  __syncthreads();
#pragma unroll
  for (int i = 0; i < 2; ++i) {
    int Gt = tid + i * 256;            // 0..511
    int nl = Gt >> 3, gq = Gt & 7;     // n-local, granule-in-64k
    int n = (z & 3) * 1024 + j0 + nl;
    bf8 v;
#pragma unroll
    for (int e = 0; e < 8; ++e) v[e] = (__bf16)T[gq * 8 + e][nl];
    if (z < 4) {
      int qp = (gq & 3) ^ ((nl >> 1) & 3);
      *(bf8*)&WxT[(size_t)n * 1024 + k0 + (gq >> 2) * 32 + qp * 8] = v;
    } else {
      *(bf8*)&WhT[(size_t)n * 1024 + k0 + gq * 8] = v;
    }
  }
}

__global__ void k_bias(const float* __restrict__ b0, const float* __restrict__ b1,
                       const float* __restrict__ b2, const float* __restrict__ b3,
                       float* __restrict__ bias) {
  int i = blockIdx.x * 256 + threadIdx.x;
  if (i < G4) {
    const float* s = (i < 1024) ? b0 : (i < 2048) ? b1 : (i < 3072) ? b2 : b3;
    bias[i] = s[i & 1023];
  }
}

// X chunk convert fp32 -> bf16, granule-swizzled (rows = m). (unchanged)
__global__ void k_convx(const float* __restrict__ X, __bf16* __restrict__ Xb,
                        int nGran) {
  int gid = blockIdx.x * 256 + threadIdx.x;
  if (gid >= nGran) return;
  int m = gid >> 7, G = gid & 127;
  const float4* s = (const float4*)(X + ((size_t)m * 1024 + G * 8));
  float4 u = s[0], v2 = s[1];
  bf8 o;
  o[0]=(__bf16)u.x; o[1]=(__bf16)u.y; o[2]=(__bf16)u.z; o[3]=(__bf16)u.w;
  o[4]=(__bf16)v2.x; o[5]=(__bf16)v2.y; o[6]=(__bf16)v2.z; o[7]=(__bf16)v2.w;
  int qp = (G & 3) ^ ((m >> 1) & 3);
  *(bf8*)&Xb[(size_t)m * 1024 + (G >> 2) * 32 + qp * 8] = o;
}

// ---------------------------------------------------------------------------
// Phase 1 GEMM (unchanged, proven): 128x128 tile, BK=32, global_load_lds.
// ---------------------------------------------------------------------------
__global__ __launch_bounds__(256) void k_gemm(const __bf16* __restrict__ A,
                                              const __bf16* __restrict__ B,
                                              const float* __restrict__ bias,
                                              float* __restrict__ C, int M) {
  __shared__ bf8 As[512];
  __shared__ bf8 Bs[512];
  int tid = threadIdx.x, lane = tid & 63, w = tid >> 6;
  int m0 = blockIdx.y * 128, n0 = blockIdx.x * 128;
  int wr = (w >> 1) * 64, wc = (w & 1) * 64;
  int lr = lane >> 2, lq = lane & 3;

  f32x4 acc[4][4] = {};

  int ra0 = m0 + w * 16 + lr;      if (ra0 > M - 1) ra0 = M - 1;
  int ra1 = m0 + 64 + w * 16 + lr; if (ra1 > M - 1) ra1 = M - 1;
  const __bf16* a0p = A + (size_t)ra0 * 1024 + lq * 8;
  const __bf16* a1p = A + (size_t)ra1 * 1024 + lq * 8;
  const __bf16* b0p = B + (size_t)(n0 + w * 16 + lr) * 1024 + lq * 8;
  const __bf16* b1p = B + (size_t)(n0 + 64 + w * 16 + lr) * 1024 + lq * 8;
  bf8* asl0 = &As[(w * 16) * 4];      bf8* asl1 = &As[(64 + w * 16) * 4];
  bf8* bsl0 = &Bs[(w * 16) * 4];      bf8* bsl1 = &Bs[(64 + w * 16) * 4];

  int r16 = lane & 15, q = lane >> 4;

  for (int kt = 0; kt < 32; ++kt) {
    __syncthreads();
    gload_lds16(a0p + kt * 32, asl0);
    gload_lds16(a1p + kt * 32, asl1);
    gload_lds16(b0p + kt * 32, bsl0);
    gload_lds16(b1p + kt * 32, bsl1);
    __syncthreads();
    bf8 af[4], bfv[4];
#pragma unroll
    for (int r = 0; r < 4; ++r) {
      int rr = wr + r * 16 + r16;
      af[r] = *(const bf8*)((const char*)As + rr * 64 + ((q ^ ((rr >> 1) & 3)) * 16));
    }
#pragma unroll
    for (int c = 0; c < 4; ++c) {
      int rr = wc + c * 16 + r16;
      bfv[c] = *(const bf8*)((const char*)Bs + rr * 64 + ((q ^ ((rr >> 1) & 3)) * 16));
    }
#pragma unroll
    for (int r = 0; r < 4; ++r)
#pragma unroll
      for (int c = 0; c < 4; ++c)
        acc[r][c] = MFMA(af[r], bfv[c], acc[r][c]);
  }

  int cj = lane & 15, hi4 = (lane >> 4) * 4;
#pragma unroll
  for (int c = 0; c < 4; ++c) {
    int col = n0 + wc + c * 16 + cj;
    float bc = bias[col];
#pragma unroll
    for (int r = 0; r < 4; ++r) {
#pragma unroll
      for (int qq = 0; qq < 4; ++qq) {
        int rr = wr + r * 16 + hi4 + qq;
        if (m0 + rr < M) C[(size_t)(m0 + rr) * G4 + col] = acc[r][c][qq] + bc;
      }
    }
  }
}

// ---------------------------------------------------------------------------
// Persistent recurrence v2: 64 blocks x 512 thr (8 waves).
// Block owns hcols [bid*16, bid*16+16) x 4 gates (64 ncols) x all 64 batches.
// Wave w: p=w&1 (ncol-quad pair), bh=(w>>1)&1 (batch half), kh=w>>2 (K half).
// Wh register-resident (Bf0/Bf1 = 128 VGPR). S register-resident per chunk.
// Per-step sync: padded per-block flags, release store + wave-parallel poll +
// single acquire load (L1/L2 invalidate) -- no contended RMW.
// ---------------------------------------------------------------------------
__global__ __launch_bounds__(512, 2) void k_recur(
    const float* __restrict__ Xg, const __bf16* __restrict__ WhT,
    __bf16* __restrict__ hb0, __bf16* __restrict__ hb1,
    float* __restrict__ S, float* __restrict__ out,
    int* flags, int t0, int Tc) {
  __shared__ bf8 Ls[64][64];                 // 64KB; aliased by Gs after MFMA
  float* Gsf = (float*)&Ls[0][0];            // Gs[kh][64][64] f32 = 2 x 16KB

  int tid = threadIdx.x, lane = tid & 63, w = tid >> 6;
  int p = w & 1, bh = (w >> 1) & 1, kh = w >> 2;
  int hc0 = blockIdx.x * 16;
  int l15 = lane & 15, lq = lane >> 4;

  // ---- Wh fragments (register resident) ----
  bf8 Bf0[16], Bf1[16];
  {
    const __bf16* w0 = WhT + (size_t)((p * 2 + 0) * 1024 + hc0 + l15) * 1024 + kh * 512 + lq * 8;
    const __bf16* w1 = WhT + (size_t)((p * 2 + 1) * 1024 + hc0 + l15) * 1024 + kh * 512 + lq * 8;
#pragma unroll
    for (int s = 0; s < 16; ++s) {
      Bf0[s] = *(const bf8*)(w0 + s * 32);
      Bf1[s] = *(const bf8*)(w1 + s * 32);
    }
  }

  // ---- cell state registers (2 elements / thread) ----
  int eb = tid >> 4, ec = tid & 15;          // b = eb / eb+32, c = ec
  float sA = 0.f, sB = 0.f;
  if (t0 > 0) {
    sA = S[(size_t)eb * 1024 + hc0 + ec];
    sB = S[(size_t)(eb + 32) * 1024 + hc0 + ec];
  }

  for (int lt = 0; lt < Tc; ++lt) {
    const int t = t0 + lt;
    f32x4 acc00 = {}, acc01 = {}, acc10 = {}, acc11 = {};

    if (t > 0) {
      if (lt > 0) {
        if (w == 0) {
          int v;
          do {
            v = __hip_atomic_load(flags + lane * 32, __ATOMIC_RELAXED,
                                  __HIP_MEMORY_SCOPE_AGENT);
          } while (!__all(v >= t));
          (void)__hip_atomic_load(flags, __ATOMIC_ACQUIRE,
                                  __HIP_MEMORY_SCOPE_AGENT);   // inv L1/L2
        }
      }
      __syncthreads();   // gate-phase LDS reads done; h visible

      const __bf16* hp = ((t - 1) & 1) ? hb1 : hb0;

#pragma unroll
      for (int kp = 0; kp < 2; ++kp) {
        // stage h[64 rows][kp*512 .. +512) -> swizzled LDS
        const __bf16* src = hp + (size_t)w * 1024 + kp * 512 + lane * 8;
        bf8 vv[8];
#pragma unroll
        for (int i = 0; i < 8; ++i) vv[i] = *(const bf8*)(src + (size_t)i * 8 * 1024);
#pragma unroll
        for (int i = 0; i < 8; ++i) {
          int r = w + i * 8;
          Ls[r][lane ^ (r & 7)] = vv[i];
        }
        __syncthreads();
        if (kh == kp) {
          int ra = bh * 32 + l15, rb = ra + 16;
#pragma unroll
          for (int s = 0; s < 16; ++s) {
            int sl = s * 4 + lq;
            bf8 afa = Ls[ra][sl ^ (ra & 7)];
            bf8 afb = Ls[rb][sl ^ (rb & 7)];
            acc00 = MFMA(afa, Bf0[s], acc00);
            acc01 = MFMA(afa, Bf1[s], acc01);
            acc10 = MFMA(afb, Bf0[s], acc10);
            acc11 = MFMA(afb, Bf1[s], acc11);
          }
        }
        __syncthreads();
      }
      // partial-sum exchange: Gs[kh][row][ncol_local]
      {
        float* G = Gsf + kh * 4096;
        int col0 = (p * 2 + 0) * 16 + l15;
        int col1 = (p * 2 + 1) * 16 + l15;
        int rw = bh * 32 + lq * 4;
#pragma unroll
        for (int q = 0; q < 4; ++q) {
          G[(rw + q) * 64 + col0] = acc00[q];
          G[(rw + q) * 64 + col1] = acc01[q];
          G[(rw + 16 + q) * 64 + col0] = acc10[q];
          G[(rw + 16 + q) * 64 + col1] = acc11[q];
        }
      }
      __syncthreads();
    }

    // ---- gates + state update (2 elements / thread) ----
    const float* xr = Xg + (size_t)lt * 64 * G4 + hc0 + ec;
    float gv0[4], gv1[4];
#pragma unroll
    for (int g = 0; g < 4; ++g) {
      float x0 = xr[(size_t)eb * G4 + g * 1024];
      float x1 = xr[(size_t)(eb + 32) * G4 + g * 1024];
      if (t > 0) {
        x0 += Gsf[eb * 64 + g * 16 + ec] + Gsf[4096 + eb * 64 + g * 16 + ec];
        x1 += Gsf[(eb + 32) * 64 + g * 16 + ec] + Gsf[4096 + (eb + 32) * 64 + g * 16 + ec];
      }
      gv0[g] = x0;
      gv1[g] = x1;
    }
    float a0 = tanh_(gv0[0]), i0 = sigf(gv0[1]), f0 = sigf(gv0[2]), o0 = sigf(gv0[3]);
    float a1 = tanh_(gv1[0]), i1 = sigf(gv1[1]), f1 = sigf(gv1[2]), o1 = sigf(gv1[3]);
    sA = a0 * i0 + sA * f0;
    sB = a1 * i1 + sB * f1;
    float h0 = tanh_(sA) * o0;
    float h1 = tanh_(sB) * o1;

    __bf16* hn = (t & 1) ? hb1 : hb0;
    out[((size_t)t * 64 + eb) * 1024 + hc0 + ec] = h0;
    out[((size_t)t * 64 + eb + 32) * 1024 + hc0 + ec] = h1;
    hn[(size_t)eb * 1024 + hc0 + ec] = (__bf16)h0;
    hn[(size_t)(eb + 32) * 1024 + hc0 + ec] = (__bf16)h1;

    __syncthreads();   // all stores drained (vmcnt) before flag release
    if (tid == 0)
      __hip_atomic_store(flags + blockIdx.x * 32, t + 1, __ATOMIC_RELEASE,
                         __HIP_MEMORY_SCOPE_AGENT);   // wbl2 + store
  }

  // persist cell state across chunk launches
  S[(size_t)eb * 1024 + hc0 + ec] = sA;
  S[(size_t)(eb + 32) * 1024 + hc0 + ec] = sB;
}

// ---------------------------------------------------------------------------
extern "C" void kernel_launch(void* const* d_in, const int* in_sizes, int n_in,
                              void* d_out, int out_size, void* d_ws, size_t ws_size,
                              hipStream_t stream) {
  const float* X  = (const float*)d_in[0];
  const float* wa = (const float*)d_in[1];
  const float* wi = (const float*)d_in[2];
  const float* wf = (const float*)d_in[3];
  const float* wo = (const float*)d_in[4];
  const float* ha = (const float*)d_in[5];
  const float* hi = (const float*)d_in[6];
  const float* hf = (const float*)d_in[7];
  const float* ho = (const float*)d_in[8];
  const float* b0 = (const float*)d_in[9];
  const float* b1 = (const float*)d_in[10];
  const float* b2 = (const float*)d_in[11];
  const float* b3 = (const float*)d_in[12];
  float* out = (float*)d_out;
  char* ws = (char*)d_ws;

  size_t off = 0;
  auto alloc = [&](size_t bytes) {
    void* p = ws + off;
    off += (bytes + 255) & ~(size_t)255;
    return p;
  };
  __bf16* WxT = (__bf16*)alloc((size_t)G4 * IDIM * 2);
  __bf16* WhT = (__bf16*)alloc((size_t)G4 * HDIM * 2);
  float* bias = (float*)alloc(G4 * 4);
  float* S    = (float*)alloc((size_t)BBATCH * HDIM * 4);
  __bf16* hb0 = (__bf16*)alloc((size_t)BBATCH * HDIM * 2);
  __bf16* hb1 = (__bf16*)alloc((size_t)BBATCH * HDIM * 2);
  int* flags  = (int*)alloc(64 * 32 * 4);
  size_t base = off;

  const size_t perT = (size_t)BBATCH * G4 * 4 + (size_t)BBATCH * IDIM * 2;
  int Tc = 64;
  while (Tc > 1 && base + (size_t)Tc * perT > ws_size) Tc >>= 1;
  float* Xg   = (float*)(ws + base);
  __bf16* Xbf = (__bf16*)(ws + base + (size_t)Tc * BBATCH * G4 * 4);

  k_convw<<<dim3(16, 16, 8), dim3(256), 0, stream>>>(wa, wi, wf, wo, ha, hi, hf,
                                                     ho, WxT, WhT);
  k_bias<<<dim3(16), dim3(256), 0, stream>>>(b0, b1, b2, b3, bias);
  hipMemsetAsync(flags, 0, 64 * 32 * 4, stream);

  for (int t0 = 0; t0 < TT; t0 += Tc) {
    int M = Tc * BBATCH;
    int nGran = M * 128;
    k_convx<<<dim3((nGran + 255) / 256), dim3(256), 0, stream>>>(
        X + (size_t)t0 * BBATCH * IDIM, Xbf, nGran);
    dim3 g1(G4 / 128, (M + 127) / 128);
    k_gemm<<<g1, dim3(256), 0, stream>>>(Xbf, WxT, bias, Xg, M);
    k_recur<<<dim3(64), dim3(512), 0, stream>>>(Xg, WhT, hb0, hb1, S, out,
                                                flags, t0, Tc);
  }
}

// Round 4
// 3697.966 us; speedup vs baseline: 2.1259x; 1.3790x over previous
//
#include <hip/hip_runtime.h>
#include <hip/hip_bf16.h>

typedef __bf16 bf8 __attribute__((ext_vector_type(8)));   // 16 B
typedef float  f32x4 __attribute__((ext_vector_type(4)));

#define TT 512
#define BBATCH 64
#define IDIM 1024
#define HDIM 1024
#define G4 4096

__device__ __forceinline__ float sigf(float x) {
  x = fminf(fmaxf(x, -30.f), 30.f);
  return 1.f / (1.f + __expf(-x));
}
__device__ __forceinline__ float tanh_(float x) {
  x = fminf(fmaxf(x, -15.f), 15.f);
  float e = __expf(2.f * x);
  return (e - 1.f) / (e + 1.f);
}
__device__ __forceinline__ f32x4 MFMA(bf8 a, bf8 b, f32x4 c) {
  return __builtin_amdgcn_mfma_f32_16x16x32_bf16(a, b, c, 0, 0, 0);
}
__device__ __forceinline__ void gload_lds16(const void* g, void* l) {
  __builtin_amdgcn_global_load_lds(
      (const __attribute__((address_space(1))) unsigned int*)g,
      (__attribute__((address_space(3))) unsigned int*)l, 16, 0, 0);
}

// ---------------------------------------------------------------------------
// Weight transpose+convert via LDS tiles. (unchanged, proven)
// ---------------------------------------------------------------------------
__global__ __launch_bounds__(256) void k_convw(
    const float* __restrict__ s0, const float* __restrict__ s1,
    const float* __restrict__ s2, const float* __restrict__ s3,
    const float* __restrict__ s4, const float* __restrict__ s5,
    const float* __restrict__ s6, const float* __restrict__ s7,
    __bf16* __restrict__ WxT, __bf16* __restrict__ WhT) {
  int z = blockIdx.z;
  const float* src = (z == 0) ? s0 : (z == 1) ? s1 : (z == 2) ? s2 :
                     (z == 3) ? s3 : (z == 4) ? s4 : (z == 5) ? s5 :
                     (z == 6) ? s6 : s7;
  int j0 = blockIdx.x * 64, k0 = blockIdx.y * 64;
  __shared__ float T[64][65];
  int tid = threadIdx.x;
#pragma unroll
  for (int i = 0; i < 16; ++i) {
    int idx = tid + i * 256;
    int kl = idx >> 6, jl = idx & 63;
    T[kl][jl] = src[(size_t)(k0 + kl) * 1024 + j0 + jl];
  }
  __syncthreads();
#pragma unroll
  for (int i = 0; i < 2; ++i) {
    int Gt = tid + i * 256;
    int nl = Gt >> 3, gq = Gt & 7;
    int n = (z & 3) * 1024 + j0 + nl;
    bf8 v;
#pragma unroll
    for (int e = 0; e < 8; ++e) v[e] = (__bf16)T[gq * 8 + e][nl];
    if (z < 4) {
      int qp = (gq & 3) ^ ((nl >> 1) & 3);
      *(bf8*)&WxT[(size_t)n * 1024 + k0 + (gq >> 2) * 32 + qp * 8] = v;
    } else {
      *(bf8*)&WhT[(size_t)n * 1024 + k0 + gq * 8] = v;
    }
  }
}

__global__ void k_bias(const float* __restrict__ b0, const float* __restrict__ b1,
                       const float* __restrict__ b2, const float* __restrict__ b3,
                       float* __restrict__ bias) {
  int i = blockIdx.x * 256 + threadIdx.x;
  if (i < G4) {
    const float* s = (i < 1024) ? b0 : (i < 2048) ? b1 : (i < 3072) ? b2 : b3;
    bias[i] = s[i & 1023];
  }
}

__global__ void k_convx(const float* __restrict__ X, __bf16* __restrict__ Xb,
                        int nGran) {
  int gid = blockIdx.x * 256 + threadIdx.x;
  if (gid >= nGran) return;
  int m = gid >> 7, G = gid & 127;
  const float4* s = (const float4*)(X + ((size_t)m * 1024 + G * 8));
  float4 u = s[0], v2 = s[1];
  bf8 o;
  o[0]=(__bf16)u.x; o[1]=(__bf16)u.y; o[2]=(__bf16)u.z; o[3]=(__bf16)u.w;
  o[4]=(__bf16)v2.x; o[5]=(__bf16)v2.y; o[6]=(__bf16)v2.z; o[7]=(__bf16)v2.w;
  int qp = (G & 3) ^ ((m >> 1) & 3);
  *(bf8*)&Xb[(size_t)m * 1024 + (G >> 2) * 32 + qp * 8] = o;
}

// ---------------------------------------------------------------------------
// Phase 1 GEMM (unchanged, proven)
// ---------------------------------------------------------------------------
__global__ __launch_bounds__(256) void k_gemm(const __bf16* __restrict__ A,
                                              const __bf16* __restrict__ B,
                                              const float* __restrict__ bias,
                                              float* __restrict__ C, int M) {
  __shared__ bf8 As[512];
  __shared__ bf8 Bs[512];
  int tid = threadIdx.x, lane = tid & 63, w = tid >> 6;
  int m0 = blockIdx.y * 128, n0 = blockIdx.x * 128;
  int wr = (w >> 1) * 64, wc = (w & 1) * 64;
  int lr = lane >> 2, lq = lane & 3;

  f32x4 acc[4][4] = {};

  int ra0 = m0 + w * 16 + lr;      if (ra0 > M - 1) ra0 = M - 1;
  int ra1 = m0 + 64 + w * 16 + lr; if (ra1 > M - 1) ra1 = M - 1;
  const __bf16* a0p = A + (size_t)ra0 * 1024 + lq * 8;
  const __bf16* a1p = A + (size_t)ra1 * 1024 + lq * 8;
  const __bf16* b0p = B + (size_t)(n0 + w * 16 + lr) * 1024 + lq * 8;
  const __bf16* b1p = B + (size_t)(n0 + 64 + w * 16 + lr) * 1024 + lq * 8;
  bf8* asl0 = &As[(w * 16) * 4];      bf8* asl1 = &As[(64 + w * 16) * 4];
  bf8* bsl0 = &Bs[(w * 16) * 4];      bf8* bsl1 = &Bs[(64 + w * 16) * 4];

  int r16 = lane & 15, q = lane >> 4;

  for (int kt = 0; kt < 32; ++kt) {
    __syncthreads();
    gload_lds16(a0p + kt * 32, asl0);
    gload_lds16(a1p + kt * 32, asl1);
    gload_lds16(b0p + kt * 32, bsl0);
    gload_lds16(b1p + kt * 32, bsl1);
    __syncthreads();
    bf8 af[4], bfv[4];
#pragma unroll
    for (int r = 0; r < 4; ++r) {
      int rr = wr + r * 16 + r16;
      af[r] = *(const bf8*)((const char*)As + rr * 64 + ((q ^ ((rr >> 1) & 3)) * 16));
    }
#pragma unroll
    for (int c = 0; c < 4; ++c) {
      int rr = wc + c * 16 + r16;
      bfv[c] = *(const bf8*)((const char*)Bs + rr * 64 + ((q ^ ((rr >> 1) & 3)) * 16));
    }
#pragma unroll
    for (int r = 0; r < 4; ++r)
#pragma unroll
      for (int c = 0; c < 4; ++c)
        acc[r][c] = MFMA(af[r], bfv[c], acc[r][c]);
  }

  int cj = lane & 15, hi4 = (lane >> 4) * 4;
#pragma unroll
  for (int c = 0; c < 4; ++c) {
    int col = n0 + wc + c * 16 + cj;
    float bc = bias[col];
#pragma unroll
    for (int r = 0; r < 4; ++r) {
#pragma unroll
      for (int qq = 0; qq < 4; ++qq) {
        int rr = wr + r * 16 + hi4 + qq;
        if (m0 + rr < M) C[(size_t)(m0 + rr) * G4 + col] = acc[r][c][qq] + bc;
      }
    }
  }
}

// ---------------------------------------------------------------------------
// Persistent recurrence v3: 64 blocks x 512 thr (8 waves).
// Structure as round 3; sync protocol rebuilt with NO cache-maintenance ops:
//   h stores  : relaxed agent atomics (sc1, write-through to LLC)
//   flag store: relaxed agent atomic AFTER __syncthreads (which drains vmcnt)
//   h loads   : relaxed agent u64 atomics (sc1, read LLC; never stale)
//   no wbl2, no buffer_inv, no RMW.
// __launch_bounds__(512,1): 256-VGPR budget -> Wh frags truly register-resident.
// ---------------------------------------------------------------------------
__global__ __launch_bounds__(512, 1) void k_recur(
    const float* __restrict__ Xg, const __bf16* __restrict__ WhT,
    __bf16* __restrict__ hb0, __bf16* __restrict__ hb1,
    float* __restrict__ S, float* __restrict__ out,
    int* flags, int t0, int Tc) {
  __shared__ bf8 Ls[64][64];                 // 64KB stage buffer
  float* Gsf = (float*)&Ls[0][0];            // alias: Gs[2][64][68] = 34.8KB

  int tid = threadIdx.x, lane = tid & 63, w = tid >> 6;
  int p = w & 1, bh = (w >> 1) & 1, kh = w >> 2;
  int hc0 = blockIdx.x * 16;
  int l15 = lane & 15, lq = lane >> 4;

  // ---- Wh fragments (register resident; 32 x bf8 = 128 VGPR) ----
  bf8 Bf0[16], Bf1[16];
  {
    const __bf16* w0 = WhT + (size_t)((p * 2 + 0) * 1024 + hc0 + l15) * 1024 + kh * 512 + lq * 8;
    const __bf16* w1 = WhT + (size_t)((p * 2 + 1) * 1024 + hc0 + l15) * 1024 + kh * 512 + lq * 8;
#pragma unroll
    for (int s = 0; s < 16; ++s) {
      Bf0[s] = *(const bf8*)(w0 + s * 32);
      Bf1[s] = *(const bf8*)(w1 + s * 32);
    }
  }

  // ---- gate-phase mapping: 1 batch x 2 adjacent cols per thread ----
  int eb = tid >> 3, ec2 = (tid & 7) * 2;
  float2 sreg = make_float2(0.f, 0.f);
  if (t0 > 0) sreg = *(const float2*)&S[(size_t)eb * 1024 + hc0 + ec2];

  for (int lt = 0; lt < Tc; ++lt) {
    const int t = t0 + lt;

    // Xg prefetch (independent of h; overlaps the poll)
    const float* xr = Xg + (size_t)lt * 64 * G4 + (size_t)eb * G4 + hc0 + ec2;
    float2 xv0 = *(const float2*)xr;
    float2 xv1 = *(const float2*)(xr + 1024);
    float2 xv2 = *(const float2*)(xr + 2048);
    float2 xv3 = *(const float2*)(xr + 3072);

    f32x4 acc00 = {}, acc01 = {}, acc10 = {}, acc11 = {};

    if (t > 0) {
      if (lt > 0) {
        if (w == 0) {
          int v;
          do {
            v = __hip_atomic_load(flags + lane * 32, __ATOMIC_RELAXED,
                                  __HIP_MEMORY_SCOPE_AGENT);
          } while (!__all(v >= t));
        }
        asm volatile("" ::: "memory");
      }
      __syncthreads();   // protects Ls (aliased Gs) reuse; orders poll

      const __bf16* hp = ((t - 1) & 1) ? hb1 : hb0;

#pragma unroll
      for (int kp = 0; kp < 2; ++kp) {
        // stage h[64 rows][kp*512 .. +512) -> swizzled LDS via LLC-coherent loads
        const unsigned long long* src8 = (const unsigned long long*)
            ((const char*)hp + ((size_t)w * 1024 + kp * 512 + lane * 8) * 2);
        bf8 vv[8];
#pragma unroll
        for (int i = 0; i < 8; ++i) {
          unsigned long long q0 = __hip_atomic_load(src8 + (size_t)i * 2048,
                                                    __ATOMIC_RELAXED,
                                                    __HIP_MEMORY_SCOPE_AGENT);
          unsigned long long q1 = __hip_atomic_load(src8 + (size_t)i * 2048 + 1,
                                                    __ATOMIC_RELAXED,
                                                    __HIP_MEMORY_SCOPE_AGENT);
          ((unsigned long long*)&vv[i])[0] = q0;
          ((unsigned long long*)&vv[i])[1] = q1;
        }
#pragma unroll
        for (int i = 0; i < 8; ++i) {
          int r = w + i * 8;
          Ls[r][lane ^ (r & 7)] = vv[i];
        }
        __syncthreads();
        if (kh == kp) {
          int ra = bh * 32 + l15, rb = ra + 16;
#pragma unroll
          for (int s = 0; s < 16; ++s) {
            int sl = s * 4 + lq;
            bf8 afa = Ls[ra][sl ^ (ra & 7)];
            bf8 afb = Ls[rb][sl ^ (rb & 7)];
            acc00 = MFMA(afa, Bf0[s], acc00);
            acc01 = MFMA(afa, Bf1[s], acc01);
            acc10 = MFMA(afb, Bf0[s], acc10);
            acc11 = MFMA(afb, Bf1[s], acc11);
          }
        }
        __syncthreads();
      }
      // partial-sum exchange: Gs[kh][row][col], row stride 68 (bank-safe)
      {
        float* G = Gsf + kh * (64 * 68);
        int col0 = (p * 2 + 0) * 16 + l15;
        int col1 = (p * 2 + 1) * 16 + l15;
        int rw = bh * 32 + lq * 4;
#pragma unroll
        for (int q = 0; q < 4; ++q) {
          G[(rw + q) * 68 + col0] = acc00[q];
          G[(rw + q) * 68 + col1] = acc01[q];
          G[(rw + 16 + q) * 68 + col0] = acc10[q];
          G[(rw + 16 + q) * 68 + col1] = acc11[q];
        }
      }
      __syncthreads();
    }

    // ---- gates + state update (1 batch x 2 cols per thread) ----
    float ga0 = xv0.x, ga1 = xv0.y;
    float gi0 = xv1.x, gi1 = xv1.y;
    float gf0 = xv2.x, gf1 = xv2.y;
    float go0 = xv3.x, go1 = xv3.y;
    if (t > 0) {
      int rb = eb * 68;
      const float* G0 = Gsf + rb;
      const float* G1 = Gsf + 64 * 68 + rb;
      ga0 += G0[ec2]      + G1[ec2];
      ga1 += G0[ec2 + 1]  + G1[ec2 + 1];
      gi0 += G0[16 + ec2]     + G1[16 + ec2];
      gi1 += G0[16 + ec2 + 1] + G1[16 + ec2 + 1];
      gf0 += G0[32 + ec2]     + G1[32 + ec2];
      gf1 += G0[32 + ec2 + 1] + G1[32 + ec2 + 1];
      go0 += G0[48 + ec2]     + G1[48 + ec2];
      go1 += G0[48 + ec2 + 1] + G1[48 + ec2 + 1];
    }
    float a0 = tanh_(ga0), i0 = sigf(gi0), f0 = sigf(gf0), o0 = sigf(go0);
    float a1 = tanh_(ga1), i1 = sigf(gi1), f1 = sigf(gf1), o1 = sigf(go1);
    sreg.x = a0 * i0 + sreg.x * f0;
    sreg.y = a1 * i1 + sreg.y * f1;
    float h0 = tanh_(sreg.x) * o0;
    float h1 = tanh_(sreg.y) * o1;

    *(float2*)&out[((size_t)t * 64 + eb) * 1024 + hc0 + ec2] = make_float2(h0, h1);

    __bf16* hn = (t & 1) ? hb1 : hb0;
    unsigned int pv = (unsigned int)__builtin_bit_cast(unsigned short, (__bf16)h0)
                    | ((unsigned int)__builtin_bit_cast(unsigned short, (__bf16)h1) << 16);
    __hip_atomic_store((unsigned int*)((char*)hn + ((size_t)eb * 1024 + hc0 + ec2) * 2),
                       pv, __ATOMIC_RELAXED, __HIP_MEMORY_SCOPE_AGENT);

    __syncthreads();   // drains vmcnt(0): all h stores complete at LLC
    if (tid == 0)
      __hip_atomic_store(flags + blockIdx.x * 32, t + 1, __ATOMIC_RELAXED,
                         __HIP_MEMORY_SCOPE_AGENT);
  }

  // persist cell state across chunk launches (normal stores; dispatch fence)
  *(float2*)&S[(size_t)eb * 1024 + hc0 + ec2] = sreg;
}

// ---------------------------------------------------------------------------
extern "C" void kernel_launch(void* const* d_in, const int* in_sizes, int n_in,
                              void* d_out, int out_size, void* d_ws, size_t ws_size,
                              hipStream_t stream) {
  const float* X  = (const float*)d_in[0];
  const float* wa = (const float*)d_in[1];
  const float* wi = (const float*)d_in[2];
  const float* wf = (const float*)d_in[3];
  const float* wo = (const float*)d_in[4];
  const float* ha = (const float*)d_in[5];
  const float* hi = (const float*)d_in[6];
  const float* hf = (const float*)d_in[7];
  const float* ho = (const float*)d_in[8];
  const float* b0 = (const float*)d_in[9];
  const float* b1 = (const float*)d_in[10];
  const float* b2 = (const float*)d_in[11];
  const float* b3 = (const float*)d_in[12];
  float* out = (float*)d_out;
  char* ws = (char*)d_ws;

  size_t off = 0;
  auto alloc = [&](size_t bytes) {
    void* p = ws + off;
    off += (bytes + 255) & ~(size_t)255;
    return p;
  };
  __bf16* WxT = (__bf16*)alloc((size_t)G4 * IDIM * 2);
  __bf16* WhT = (__bf16*)alloc((size_t)G4 * HDIM * 2);
  float* bias = (float*)alloc(G4 * 4);
  float* S    = (float*)alloc((size_t)BBATCH * HDIM * 4);
  __bf16* hb0 = (__bf16*)alloc((size_t)BBATCH * HDIM * 2);
  __bf16* hb1 = (__bf16*)alloc((size_t)BBATCH * HDIM * 2);
  int* flags  = (int*)alloc(64 * 32 * 4);
  size_t base = off;

  const size_t perT = (size_t)BBATCH * G4 * 4 + (size_t)BBATCH * IDIM * 2;
  int Tc = 64;
  while (Tc > 1 && base + (size_t)Tc * perT > ws_size) Tc >>= 1;
  float* Xg   = (float*)(ws + base);
  __bf16* Xbf = (__bf16*)(ws + base + (size_t)Tc * BBATCH * G4 * 4);

  k_convw<<<dim3(16, 16, 8), dim3(256), 0, stream>>>(wa, wi, wf, wo, ha, hi, hf,
                                                     ho, WxT, WhT);
  k_bias<<<dim3(16), dim3(256), 0, stream>>>(b0, b1, b2, b3, bias);
  hipMemsetAsync(flags, 0, 64 * 32 * 4, stream);

  for (int t0 = 0; t0 < TT; t0 += Tc) {
    int M = Tc * BBATCH;
    int nGran = M * 128;
    k_convx<<<dim3((nGran + 255) / 256), dim3(256), 0, stream>>>(
        X + (size_t)t0 * BBATCH * IDIM, Xbf, nGran);
    dim3 g1(G4 / 128, (M + 127) / 128);
    k_gemm<<<g1, dim3(256), 0, stream>>>(Xbf, WxT, bias, Xg, M);
    k_recur<<<dim3(64), dim3(512), 0, stream>>>(Xg, WhT, hb0, hb1, S, out,
                                                flags, t0, Tc);
  }
}

// Round 6
// 2363.966 us; speedup vs baseline: 3.3256x; 1.5643x over previous
//
#include <hip/hip_runtime.h>
#include <hip/hip_bf16.h>

typedef __bf16 bf8 __attribute__((ext_vector_type(8)));   // 16 B
typedef float  f32x4 __attribute__((ext_vector_type(4)));
typedef unsigned long long u64;

#define TT 512
#define BBATCH 64
#define IDIM 1024
#define HDIM 1024
#define G4 4096
#define NREC 128

__device__ __forceinline__ float sigf(float x) {
  x = fminf(fmaxf(x, -30.f), 30.f);
  return 1.f / (1.f + __expf(-x));
}
__device__ __forceinline__ float tanh_(float x) {
  x = fminf(fmaxf(x, -15.f), 15.f);
  float e = __expf(2.f * x);
  return (e - 1.f) / (e + 1.f);
}
__device__ __forceinline__ f32x4 MFMA(bf8 a, bf8 b, f32x4 c) {
  return __builtin_amdgcn_mfma_f32_16x16x32_bf16(a, b, c, 0, 0, 0);
}

// ---------------------------------------------------------------------------
// Weight transpose+convert via LDS tiles (plain [n][k] bf16 for BOTH Wx, Wh).
// n = gate*1024 + j, gate order a,i,f,o.
// ---------------------------------------------------------------------------
__global__ __launch_bounds__(256) void k_convw(
    const float* __restrict__ s0, const float* __restrict__ s1,
    const float* __restrict__ s2, const float* __restrict__ s3,
    const float* __restrict__ s4, const float* __restrict__ s5,
    const float* __restrict__ s6, const float* __restrict__ s7,
    __bf16* __restrict__ WxT, __bf16* __restrict__ WhT) {
  int z = blockIdx.z;
  const float* src = (z == 0) ? s0 : (z == 1) ? s1 : (z == 2) ? s2 :
                     (z == 3) ? s3 : (z == 4) ? s4 : (z == 5) ? s5 :
                     (z == 6) ? s6 : s7;
  __bf16* dst = (z < 4) ? WxT : WhT;
  int j0 = blockIdx.x * 64, k0 = blockIdx.y * 64;
  __shared__ float T[64][65];
  int tid = threadIdx.x;
#pragma unroll
  for (int i = 0; i < 16; ++i) {
    int idx = tid + i * 256;
    int kl = idx >> 6, jl = idx & 63;
    T[kl][jl] = src[(size_t)(k0 + kl) * 1024 + j0 + jl];
  }
  __syncthreads();
#pragma unroll
  for (int i = 0; i < 2; ++i) {
    int Gt = tid + i * 256;            // 0..511
    int nl = Gt >> 3, gq = Gt & 7;     // n-local, granule
    int n = (z & 3) * 1024 + j0 + nl;
    bf8 v;
#pragma unroll
    for (int e = 0; e < 8; ++e) v[e] = (__bf16)T[gq * 8 + e][nl];
    *(bf8*)&dst[(size_t)n * 1024 + k0 + gq * 8] = v;
  }
}

__global__ void k_bias(const float* __restrict__ b0, const float* __restrict__ b1,
                       const float* __restrict__ b2, const float* __restrict__ b3,
                       float* __restrict__ bias) {
  int i = blockIdx.x * 256 + threadIdx.x;
  if (i < G4) {
    const float* s = (i < 1024) ? b0 : (i < 2048) ? b1 : (i < 3072) ? b2 : b3;
    bias[i] = s[i & 1023];
  }
}

// ---------------------------------------------------------------------------
// Fused persistent kernel. grid = 256 x 512 threads, 64KB LDS -> all resident.
//  blocks [0, nrec):    recurrence for chunk starting at t0 (Tc steps)
//  blocks [nrec, 256):  GEMM Xg_w = Xnext @ WxT^T + bias (next chunk's gates)
// ---------------------------------------------------------------------------
__global__ __launch_bounds__(512, 1) void k_fused(
    const float* __restrict__ Xg_r, float* __restrict__ Xg_w,
    const __bf16* __restrict__ WhT, const __bf16* __restrict__ WxT,
    const float* __restrict__ Xnext, const float* __restrict__ bias,
    __bf16* __restrict__ hb0, __bf16* __restrict__ hb1,
    float* __restrict__ S, float* __restrict__ out,
    int* flags, int t0, int Tc, int nrec, int gM) {
  __shared__ char smem[65536];
  const int bid = blockIdx.x, tid = threadIdx.x;
  const int lane = tid & 63, w = tid >> 6;

  if (bid < nrec) {
    // =================== recurrence ===================
    bf8 (*Ls)[128] = (bf8(*)[128])smem;      // [32 rows][128 granules]
    float* Gsf = (float*)smem;               // alias: Gs[4][32][68]
    const int kh = w >> 1, bh = w & 1;
    const int rh = bid & 1, hc0 = (bid >> 1) * 16;
    const int l15 = lane & 15, lq = lane >> 4;
    const int rowbase = rh * 32;
    const int br = bh * 16 + l15;            // local batch row for A-frags

    // ---- Wh fragments: ncol = ct*1024 + hc0 + l15, k = kh*256 + s*32 + lq*8
    bf8 Bf[32];
#pragma unroll
    for (int ct = 0; ct < 4; ++ct)
#pragma unroll
      for (int s = 0; s < 8; ++s)
        Bf[ct * 8 + s] = *(const bf8*)&WhT[(size_t)(ct * 1024 + hc0 + l15) * 1024 +
                                           kh * 256 + s * 32 + lq * 8];
    // pin in registers: value-level opaque pass-through (no address taken)
#pragma unroll
    for (int i = 0; i < 32; ++i) {
      float4 t = __builtin_bit_cast(float4, Bf[i]);
      asm volatile("" : "+v"(t.x), "+v"(t.y), "+v"(t.z), "+v"(t.w));
      Bf[i] = __builtin_bit_cast(bf8, t);
    }

    // ---- gate-phase mapping: 1 (batch,col) per thread ----
    const int er = tid >> 4, ec = tid & 15;  // er in [0,32), ec in [0,16)
    float sreg = 0.f;
    if (t0 > 0) sreg = S[(size_t)(rowbase + er) * 1024 + hc0 + ec];

    for (int lt = 0; lt < Tc; ++lt) {
      const int t = t0 + lt;

      // Xg prefetch (independent of h, overlaps poll)
      const float* xp = Xg_r + ((size_t)lt * 64 + rowbase + er) * G4 + hc0 + ec;
      float xa = xp[0], xi = xp[1024], xf = xp[2048], xo = xp[3072];

      if (t > 0) {
        if (lt > 0) {
          int v0, v1;
          do {
            v0 = __hip_atomic_load(flags + lane * 32, __ATOMIC_RELAXED,
                                   __HIP_MEMORY_SCOPE_AGENT);
            v1 = __hip_atomic_load(flags + (lane + 64) * 32, __ATOMIC_RELAXED,
                                   __HIP_MEMORY_SCOPE_AGENT);
          } while (!__all(v0 >= t && v1 >= t));
          asm volatile("" ::: "memory");   // no hoisting h-loads above poll
        }
        const __bf16* hp = ((t - 1) & 1) ? hb1 : hb0;

        // stage h[rowbase..+32)[0..1024) -> swizzled LDS (8 granules/thread)
        union { u64 q[2]; bf8 v; } vv[8];
#pragma unroll
        for (int i = 0; i < 8; ++i) {
          int g = i * 512 + tid;
          const u64* sp = (const u64*)(hp + (size_t)(rowbase + (g >> 7)) * 1024 +
                                       (g & 127) * 8);
          vv[i].q[0] = __hip_atomic_load((u64*)sp, __ATOMIC_RELAXED,
                                         __HIP_MEMORY_SCOPE_AGENT);
          vv[i].q[1] = __hip_atomic_load((u64*)sp + 1, __ATOMIC_RELAXED,
                                         __HIP_MEMORY_SCOPE_AGENT);
        }
#pragma unroll
        for (int i = 0; i < 8; ++i) {
          int g = i * 512 + tid, r = g >> 7, cg = g & 127;
          Ls[r][cg ^ (r & 7)] = vv[i].v;
        }
        __syncthreads();

        f32x4 a0 = {}, a1 = {}, a2 = {}, a3 = {};
#pragma unroll
        for (int s = 0; s < 8; ++s) {
          bf8 af = Ls[br][(kh * 32 + s * 4 + lq) ^ (br & 7)];
          a0 = MFMA(af, Bf[s], a0);
          a1 = MFMA(af, Bf[8 + s], a1);
          a2 = MFMA(af, Bf[16 + s], a2);
          a3 = MFMA(af, Bf[24 + s], a3);
        }
        __syncthreads();   // all Ls reads done before Gs alias-write

        {
          float* G = Gsf + kh * (32 * 68) + (bh * 16 + lq * 4) * 68 + l15;
#pragma unroll
          for (int q = 0; q < 4; ++q) {
            G[q * 68 + 0]  = a0[q];
            G[q * 68 + 16] = a1[q];
            G[q * 68 + 32] = a2[q];
            G[q * 68 + 48] = a3[q];
          }
        }
        __syncthreads();

        const float* Gr = Gsf + er * 68 + ec;
#pragma unroll
        for (int k2 = 0; k2 < 4; ++k2) {
          xa += Gr[k2 * 2176 + 0];
          xi += Gr[k2 * 2176 + 16];
          xf += Gr[k2 * 2176 + 32];
          xo += Gr[k2 * 2176 + 48];
        }
      }

      // ---- gates + state update ----
      float av = tanh_(xa), iv = sigf(xi), fv = sigf(xf), ov = sigf(xo);
      sreg = av * iv + sreg * fv;
      float h0 = tanh_(sreg) * ov;

      out[((size_t)t * 64 + rowbase + er) * 1024 + hc0 + ec] = h0;

      // packed u32 agent store of h (pairs of adjacent cols via shfl)
      float hnb = __shfl(h0, lane + 1);
      if ((ec & 1) == 0) {
        unsigned int pv =
            (unsigned int)__builtin_bit_cast(unsigned short, (__bf16)h0) |
            ((unsigned int)__builtin_bit_cast(unsigned short, (__bf16)hnb) << 16);
        __bf16* hn = (t & 1) ? hb1 : hb0;
        __hip_atomic_store(
            (unsigned int*)((char*)hn + ((size_t)(rowbase + er) * 1024 + hc0 + ec) * 2),
            pv, __ATOMIC_RELAXED, __HIP_MEMORY_SCOPE_AGENT);
      }

      __syncthreads();   // drains vmcnt(0): h stores complete at LLC
      if (tid == 0)
        __hip_atomic_store(flags + bid * 32, t + 1, __ATOMIC_RELAXED,
                           __HIP_MEMORY_SCOPE_AGENT);
    }

    S[(size_t)(rowbase + er) * 1024 + hc0 + ec] = sreg;
    return;
  }

  // =================== worker GEMM (next chunk's Xg) ===================
  if (gM == 0) return;
  const int nw = gridDim.x - nrec;
  const int wid = bid - nrec;
  __bf16 (*As)[40] = (__bf16(*)[40])smem;                 // 10240 B
  __bf16 (*Bs)[40] = (__bf16(*)[40])(smem + 128 * 40 * 2);
  const int wr = (w >> 2) * 64, wc = (w & 3) * 32;
  const int sm = tid >> 2, sk = (tid & 3) * 8;
  const int gl15 = lane & 15, glq = lane >> 4;
  const int ntiles = (gM / 128) * (G4 / 128);

  for (int tile = wid; tile < ntiles; tile += nw) {
    const int m0 = (tile >> 5) * 128, n0 = (tile & 31) * 128;
    const float*  Ap = Xnext + (size_t)(m0 + sm) * 1024 + sk;
    const __bf16* Bp = WxT + (size_t)(n0 + sm) * 1024 + sk;
    f32x4 acc[4][2] = {};
    float4 ra0, ra1;
    bf8 rb;
    auto ld = [&](int kt) {
      ra0 = *(const float4*)(Ap + kt * 32);
      ra1 = *(const float4*)(Ap + kt * 32 + 4);
      rb = *(const bf8*)(Bp + kt * 32);
    };
    ld(0);
    for (int kt = 0; kt < 32; ++kt) {
      __syncthreads();
      bf8 va;
      va[0]=(__bf16)ra0.x; va[1]=(__bf16)ra0.y; va[2]=(__bf16)ra0.z; va[3]=(__bf16)ra0.w;
      va[4]=(__bf16)ra1.x; va[5]=(__bf16)ra1.y; va[6]=(__bf16)ra1.z; va[7]=(__bf16)ra1.w;
      *(bf8*)&As[sm][sk] = va;
      *(bf8*)&Bs[sm][sk] = rb;
      if (kt < 31) ld(kt + 1);
      __syncthreads();
      bf8 af[4], bv[2];
#pragma unroll
      for (int r = 0; r < 4; ++r) af[r] = *(const bf8*)&As[wr + r * 16 + gl15][glq * 8];
#pragma unroll
      for (int c = 0; c < 2; ++c) bv[c] = *(const bf8*)&Bs[wc + c * 16 + gl15][glq * 8];
#pragma unroll
      for (int r = 0; r < 4; ++r)
#pragma unroll
        for (int c = 0; c < 2; ++c)
          acc[r][c] = MFMA(af[r], bv[c], acc[r][c]);
    }
#pragma unroll
    for (int c = 0; c < 2; ++c) {
      int col = n0 + wc + c * 16 + gl15;
      float bc = bias[col];
#pragma unroll
      for (int r = 0; r < 4; ++r)
#pragma unroll
        for (int q = 0; q < 4; ++q)
          Xg_w[(size_t)(m0 + wr + r * 16 + glq * 4 + q) * G4 + col] = acc[r][c][q] + bc;
    }
    __syncthreads();   // LDS reuse across tiles
  }
}

// ---------------------------------------------------------------------------
extern "C" void kernel_launch(void* const* d_in, const int* in_sizes, int n_in,
                              void* d_out, int out_size, void* d_ws, size_t ws_size,
                              hipStream_t stream) {
  const float* X  = (const float*)d_in[0];
  const float* wa = (const float*)d_in[1];
  const float* wi = (const float*)d_in[2];
  const float* wf = (const float*)d_in[3];
  const float* wo = (const float*)d_in[4];
  const float* ha = (const float*)d_in[5];
  const float* hi = (const float*)d_in[6];
  const float* hf = (const float*)d_in[7];
  const float* ho = (const float*)d_in[8];
  const float* b0 = (const float*)d_in[9];
  const float* b1 = (const float*)d_in[10];
  const float* b2 = (const float*)d_in[11];
  const float* b3 = (const float*)d_in[12];
  float* out = (float*)d_out;
  char* ws = (char*)d_ws;

  size_t off = 0;
  auto alloc = [&](size_t bytes) {
    void* p = ws + off;
    off += (bytes + 255) & ~(size_t)255;
    return p;
  };
  __bf16* WxT = (__bf16*)alloc((size_t)G4 * IDIM * 2);
  __bf16* WhT = (__bf16*)alloc((size_t)G4 * HDIM * 2);
  float* bias = (float*)alloc(G4 * 4);
  float* S    = (float*)alloc((size_t)BBATCH * HDIM * 4);
  __bf16* hb0 = (__bf16*)alloc((size_t)BBATCH * HDIM * 2);
  __bf16* hb1 = (__bf16*)alloc((size_t)BBATCH * HDIM * 2);
  int* flags  = (int*)alloc(NREC * 32 * 4);
  size_t base = off;

  const size_t perXg = (size_t)BBATCH * G4 * 4;  // 1 MB per timestep
  int Tc = 64;
  while (Tc > 4 && base + 2 * (size_t)Tc * perXg > ws_size) Tc >>= 1;
  float* Xg0 = (float*)(ws + base);
  float* Xg1 = (float*)(ws + base + (size_t)Tc * perXg);
  int nchunks = TT / Tc;

  k_convw<<<dim3(16, 16, 8), dim3(256), 0, stream>>>(wa, wi, wf, wo, ha, hi, hf,
                                                     ho, WxT, WhT);
  k_bias<<<dim3(16), dim3(256), 0, stream>>>(b0, b1, b2, b3, bias);
  hipMemsetAsync(flags, 0, NREC * 32 * 4, stream);

  // prologue: all 256 blocks compute chunk 0's Xg
  k_fused<<<dim3(256), dim3(512), 0, stream>>>(
      nullptr, Xg0, WhT, WxT, X, bias, hb0, hb1, S, out, flags,
      0, 0, /*nrec=*/0, /*gM=*/Tc * BBATCH);

  for (int c = 0; c < nchunks; ++c) {
    float* xr = (c & 1) ? Xg1 : Xg0;
    float* xw = (c & 1) ? Xg0 : Xg1;
    int gM = (c + 1 < nchunks) ? Tc * BBATCH : 0;
    const float* Xn = X + (size_t)(c + 1) * Tc * BBATCH * IDIM;
    k_fused<<<dim3(256), dim3(512), 0, stream>>>(
        xr, xw, WhT, WxT, Xn, bias, hb0, hb1, S, out, flags,
        c * Tc, Tc, /*nrec=*/NREC, gM);
  }
}

// Round 7
// 2227.420 us; speedup vs baseline: 3.5294x; 1.0613x over previous
//
#include <hip/hip_runtime.h>
#include <hip/hip_bf16.h>

typedef __bf16 bf8 __attribute__((ext_vector_type(8)));   // 16 B
typedef float  f32x4 __attribute__((ext_vector_type(4)));
typedef unsigned long long u64;

#define TT 512
#define BBATCH 64
#define IDIM 1024
#define HDIM 1024
#define G4 4096
#define NREC 128

__device__ __forceinline__ float sigf(float x) {
  x = fminf(fmaxf(x, -30.f), 30.f);
  return 1.f / (1.f + __expf(-x));
}
__device__ __forceinline__ float tanh_(float x) {
  x = fminf(fmaxf(x, -15.f), 15.f);
  float e = __expf(2.f * x);
  return (e - 1.f) / (e + 1.f);
}
__device__ __forceinline__ f32x4 MFMA(bf8 a, bf8 b, f32x4 c) {
  return __builtin_amdgcn_mfma_f32_16x16x32_bf16(a, b, c, 0, 0, 0);
}

// ---------------------------------------------------------------------------
// Weight transpose+convert via LDS tiles (plain [n][k] bf16 for BOTH Wx, Wh).
// n = gate*1024 + j, gate order a,i,f,o.
// ---------------------------------------------------------------------------
__global__ __launch_bounds__(256) void k_convw(
    const float* __restrict__ s0, const float* __restrict__ s1,
    const float* __restrict__ s2, const float* __restrict__ s3,
    const float* __restrict__ s4, const float* __restrict__ s5,
    const float* __restrict__ s6, const float* __restrict__ s7,
    __bf16* __restrict__ WxT, __bf16* __restrict__ WhT) {
  int z = blockIdx.z;
  const float* src = (z == 0) ? s0 : (z == 1) ? s1 : (z == 2) ? s2 :
                     (z == 3) ? s3 : (z == 4) ? s4 : (z == 5) ? s5 :
                     (z == 6) ? s6 : s7;
  __bf16* dst = (z < 4) ? WxT : WhT;
  int j0 = blockIdx.x * 64, k0 = blockIdx.y * 64;
  __shared__ float T[64][65];
  int tid = threadIdx.x;
#pragma unroll
  for (int i = 0; i < 16; ++i) {
    int idx = tid + i * 256;
    int kl = idx >> 6, jl = idx & 63;
    T[kl][jl] = src[(size_t)(k0 + kl) * 1024 + j0 + jl];
  }
  __syncthreads();
#pragma unroll
  for (int i = 0; i < 2; ++i) {
    int Gt = tid + i * 256;            // 0..511
    int nl = Gt >> 3, gq = Gt & 7;     // n-local, granule
    int n = (z & 3) * 1024 + j0 + nl;
    bf8 v;
#pragma unroll
    for (int e = 0; e < 8; ++e) v[e] = (__bf16)T[gq * 8 + e][nl];
    *(bf8*)&dst[(size_t)n * 1024 + k0 + gq * 8] = v;
  }
}

__global__ void k_bias(const float* __restrict__ b0, const float* __restrict__ b1,
                       const float* __restrict__ b2, const float* __restrict__ b3,
                       float* __restrict__ bias) {
  int i = blockIdx.x * 256 + threadIdx.x;
  if (i < G4) {
    const float* s = (i < 1024) ? b0 : (i < 2048) ? b1 : (i < 3072) ? b2 : b3;
    bias[i] = s[i & 1023];
  }
}

// ---------------------------------------------------------------------------
// Fused persistent kernel. grid = 256 x 512 threads, 64KB LDS.
//  blocks [0, nrec):    recurrence for chunk starting at t0 (Tc steps)
//  blocks [nrec, 256):  GEMM Xg_w = Xnext @ WxT^T + bias (next chunk's gates)
//
// Recurrence block bid: rh = bid&1 (batch rows rh*32..+32), hc0 = (bid>>1)*16.
// Wave w: ct = w&3 (gate), kh = w>>2 (K half). B-tiles DISJOINT across waves:
// Bf = 16 x bf8 = 64 VGPR per wave -> truly register resident.
// Poll: only the 64 same-rh producer flags (batch halves decoupled).
// ---------------------------------------------------------------------------
__global__ __launch_bounds__(512, 2) void k_fused(
    const float* __restrict__ Xg_r, float* __restrict__ Xg_w,
    const __bf16* __restrict__ WhT, const __bf16* __restrict__ WxT,
    const float* __restrict__ Xnext, const float* __restrict__ bias,
    __bf16* __restrict__ hb0, __bf16* __restrict__ hb1,
    float* __restrict__ S, float* __restrict__ out,
    int* flags, int t0, int Tc, int nrec, int gM) {
  __shared__ char smem[65536];
  const int bid = blockIdx.x, tid = threadIdx.x;
  const int lane = tid & 63, w = tid >> 6;

  if (bid < nrec) {
    // =================== recurrence ===================
    bf8 (*Ls)[128] = (bf8(*)[128])smem;      // [32 rows][128 granules] = 64KB
    float* Gsf = (float*)smem;               // alias: Gs[2][32][68] = 17.4KB
    const int ct = w & 3, kh = w >> 2;
    const int rh = bid & 1, hc0 = (bid >> 1) * 16;
    const int l15 = lane & 15, lq = lane >> 4;
    const int rowbase = rh * 32;

    // ---- Wh fragments: ncol = ct*1024 + hc0 + l15, k = kh*512 + s*32 + lq*8
    bf8 Bf[16];
#pragma unroll
    for (int s = 0; s < 16; ++s)
      Bf[s] = *(const bf8*)&WhT[(size_t)(ct * 1024 + hc0 + l15) * 1024 +
                                kh * 512 + s * 32 + lq * 8];
    // pin values in registers (prevents re-load/remat inside the loop)
#pragma unroll
    for (int i = 0; i < 16; ++i) {
      float4 tpin = __builtin_bit_cast(float4, Bf[i]);
      asm volatile("" : "+v"(tpin.x), "+v"(tpin.y), "+v"(tpin.z), "+v"(tpin.w));
      Bf[i] = __builtin_bit_cast(bf8, tpin);
    }

    // ---- gate-phase mapping: 1 (batch,col) per thread ----
    const int er = tid >> 4, ec = tid & 15;  // er in [0,32), ec in [0,16)
    float sreg = 0.f;
    if (t0 > 0) sreg = S[(size_t)(rowbase + er) * 1024 + hc0 + ec];

    for (int lt = 0; lt < Tc; ++lt) {
      const int t = t0 + lt;

      // Xg prefetch (independent of h, overlaps poll)
      const float* xp = Xg_r + ((size_t)lt * 64 + rowbase + er) * G4 + hc0 + ec;
      float xa = xp[0], xi = xp[1024], xf = xp[2048], xo = xp[3072];

      f32x4 acc0 = {}, acc1 = {};

      if (t > 0) {
        if (lt > 0) {
          // poll only same-rh producers (64 flags, one per lane)
          int v;
          do {
            v = __hip_atomic_load(flags + (2 * lane + rh) * 32, __ATOMIC_RELAXED,
                                  __HIP_MEMORY_SCOPE_AGENT);
          } while (!__all(v >= t));
          asm volatile("" ::: "memory");   // no hoisting h-loads above poll
        }
        const __bf16* hp = ((t - 1) & 1) ? hb1 : hb0;

        // stage h[rowbase..+32)[0..1024) -> swizzled LDS (8 granules/thread)
        union { u64 q[2]; bf8 v; } vv[8];
#pragma unroll
        for (int i = 0; i < 8; ++i) {
          int g = i * 512 + tid;
          const u64* sp = (const u64*)(hp + (size_t)(rowbase + (g >> 7)) * 1024 +
                                       (g & 127) * 8);
          vv[i].q[0] = __hip_atomic_load((u64*)sp, __ATOMIC_RELAXED,
                                         __HIP_MEMORY_SCOPE_AGENT);
          vv[i].q[1] = __hip_atomic_load((u64*)sp + 1, __ATOMIC_RELAXED,
                                         __HIP_MEMORY_SCOPE_AGENT);
        }
#pragma unroll
        for (int i = 0; i < 8; ++i) {
          int g = i * 512 + tid, r = g >> 7, cg = g & 127;
          Ls[r][cg ^ (r & 7)] = vv[i].v;
        }
        __syncthreads();

        // MFMA: wave (ct,kh) computes gate ct, K-half kh, all 32 rows
#pragma unroll
        for (int s = 0; s < 16; ++s) {
          int kk = kh * 64 + s * 4 + lq;
          bf8 af0 = Ls[l15][kk ^ (l15 & 7)];
          bf8 af1 = Ls[16 + l15][kk ^ (l15 & 7)];
          acc0 = MFMA(af0, Bf[s], acc0);
          acc1 = MFMA(af1, Bf[s], acc1);
        }
        __syncthreads();   // all Ls reads done before Gs alias-write

        {
          float* G = Gsf + kh * 2176 + ct * 16 + l15;
#pragma unroll
          for (int q = 0; q < 4; ++q) {
            G[(lq * 4 + q) * 68]        = acc0[q];
            G[(16 + lq * 4 + q) * 68]   = acc1[q];
          }
        }
        __syncthreads();

        const float* Gr = Gsf + er * 68 + ec;
        xa += Gr[0]  + Gr[2176 + 0];
        xi += Gr[16] + Gr[2176 + 16];
        xf += Gr[32] + Gr[2176 + 32];
        xo += Gr[48] + Gr[2176 + 48];
      }

      // ---- gates + state update ----
      float av = tanh_(xa), iv = sigf(xi), fv = sigf(xf), ov = sigf(xo);
      sreg = av * iv + sreg * fv;
      float h0 = tanh_(sreg) * ov;

      out[((size_t)t * 64 + rowbase + er) * 1024 + hc0 + ec] = h0;

      // packed u32 agent store of h (pairs of adjacent cols via shfl)
      float hnb = __shfl(h0, lane + 1);
      if ((ec & 1) == 0) {
        unsigned int pv =
            (unsigned int)__builtin_bit_cast(unsigned short, (__bf16)h0) |
            ((unsigned int)__builtin_bit_cast(unsigned short, (__bf16)hnb) << 16);
        __bf16* hn = (t & 1) ? hb1 : hb0;
        __hip_atomic_store(
            (unsigned int*)((char*)hn + ((size_t)(rowbase + er) * 1024 + hc0 + ec) * 2),
            pv, __ATOMIC_RELAXED, __HIP_MEMORY_SCOPE_AGENT);
      }

      __syncthreads();   // drains vmcnt(0): h stores complete at LLC
      if (tid == 0)
        __hip_atomic_store(flags + bid * 32, t + 1, __ATOMIC_RELAXED,
                           __HIP_MEMORY_SCOPE_AGENT);
    }

    S[(size_t)(rowbase + er) * 1024 + hc0 + ec] = sreg;
    return;
  }

  // =================== worker GEMM (next chunk's Xg) ===================
  if (gM == 0) return;
  const int nw = gridDim.x - nrec;
  const int wid = bid - nrec;
  __bf16 (*As)[40] = (__bf16(*)[40])smem;                 // 10240 B
  __bf16 (*Bs)[40] = (__bf16(*)[40])(smem + 128 * 40 * 2);
  const int wr = (w >> 2) * 64, wc = (w & 3) * 32;
  const int sm = tid >> 2, sk = (tid & 3) * 8;
  const int gl15 = lane & 15, glq = lane >> 4;
  const int ntiles = (gM / 128) * (G4 / 128);

  for (int tile = wid; tile < ntiles; tile += nw) {
    const int m0 = (tile >> 5) * 128, n0 = (tile & 31) * 128;
    const float*  Ap = Xnext + (size_t)(m0 + sm) * 1024 + sk;
    const __bf16* Bp = WxT + (size_t)(n0 + sm) * 1024 + sk;
    f32x4 acc[4][2] = {};
    float4 ra0, ra1;
    bf8 rb;
    auto ld = [&](int kt) {
      ra0 = *(const float4*)(Ap + kt * 32);
      ra1 = *(const float4*)(Ap + kt * 32 + 4);
      rb = *(const bf8*)(Bp + kt * 32);
    };
    ld(0);
    for (int kt = 0; kt < 32; ++kt) {
      __syncthreads();
      bf8 va;
      va[0]=(__bf16)ra0.x; va[1]=(__bf16)ra0.y; va[2]=(__bf16)ra0.z; va[3]=(__bf16)ra0.w;
      va[4]=(__bf16)ra1.x; va[5]=(__bf16)ra1.y; va[6]=(__bf16)ra1.z; va[7]=(__bf16)ra1.w;
      *(bf8*)&As[sm][sk] = va;
      *(bf8*)&Bs[sm][sk] = rb;
      if (kt < 31) ld(kt + 1);
      __syncthreads();
      bf8 af[4], bv[2];
#pragma unroll
      for (int r = 0; r < 4; ++r) af[r] = *(const bf8*)&As[wr + r * 16 + gl15][glq * 8];
#pragma unroll
      for (int c = 0; c < 2; ++c) bv[c] = *(const bf8*)&Bs[wc + c * 16 + gl15][glq * 8];
#pragma unroll
      for (int r = 0; r < 4; ++r)
#pragma unroll
        for (int c = 0; c < 2; ++c)
          acc[r][c] = MFMA(af[r], bv[c], acc[r][c]);
    }
#pragma unroll
    for (int c = 0; c < 2; ++c) {
      int col = n0 + wc + c * 16 + gl15;
      float bc = bias[col];
#pragma unroll
      for (int r = 0; r < 4; ++r)
#pragma unroll
        for (int q = 0; q < 4; ++q)
          Xg_w[(size_t)(m0 + wr + r * 16 + glq * 4 + q) * G4 + col] = acc[r][c][q] + bc;
    }
    __syncthreads();   // LDS reuse across tiles
  }
}

// ---------------------------------------------------------------------------
extern "C" void kernel_launch(void* const* d_in, const int* in_sizes, int n_in,
                              void* d_out, int out_size, void* d_ws, size_t ws_size,
                              hipStream_t stream) {
  const float* X  = (const float*)d_in[0];
  const float* wa = (const float*)d_in[1];
  const float* wi = (const float*)d_in[2];
  const float* wf = (const float*)d_in[3];
  const float* wo = (const float*)d_in[4];
  const float* ha = (const float*)d_in[5];
  const float* hi = (const float*)d_in[6];
  const float* hf = (const float*)d_in[7];
  const float* ho = (const float*)d_in[8];
  const float* b0 = (const float*)d_in[9];
  const float* b1 = (const float*)d_in[10];
  const float* b2 = (const float*)d_in[11];
  const float* b3 = (const float*)d_in[12];
  float* out = (float*)d_out;
  char* ws = (char*)d_ws;

  size_t off = 0;
  auto alloc = [&](size_t bytes) {
    void* p = ws + off;
    off += (bytes + 255) & ~(size_t)255;
    return p;
  };
  __bf16* WxT = (__bf16*)alloc((size_t)G4 * IDIM * 2);
  __bf16* WhT = (__bf16*)alloc((size_t)G4 * HDIM * 2);
  float* bias = (float*)alloc(G4 * 4);
  float* S    = (float*)alloc((size_t)BBATCH * HDIM * 4);
  __bf16* hb0 = (__bf16*)alloc((size_t)BBATCH * HDIM * 2);
  __bf16* hb1 = (__bf16*)alloc((size_t)BBATCH * HDIM * 2);
  int* flags  = (int*)alloc(NREC * 32 * 4);
  size_t base = off;

  const size_t perXg = (size_t)BBATCH * G4 * 4;  // 1 MB per timestep
  int Tc = 64;
  while (Tc > 4 && base + 2 * (size_t)Tc * perXg > ws_size) Tc >>= 1;
  float* Xg0 = (float*)(ws + base);
  float* Xg1 = (float*)(ws + base + (size_t)Tc * perXg);
  int nchunks = TT / Tc;

  k_convw<<<dim3(16, 16, 8), dim3(256), 0, stream>>>(wa, wi, wf, wo, ha, hi, hf,
                                                     ho, WxT, WhT);
  k_bias<<<dim3(16), dim3(256), 0, stream>>>(b0, b1, b2, b3, bias);
  hipMemsetAsync(flags, 0, NREC * 32 * 4, stream);

  // prologue: all 256 blocks compute chunk 0's Xg
  k_fused<<<dim3(256), dim3(512), 0, stream>>>(
      nullptr, Xg0, WhT, WxT, X, bias, hb0, hb1, S, out, flags,
      0, 0, /*nrec=*/0, /*gM=*/Tc * BBATCH);

  for (int c = 0; c < nchunks; ++c) {
    float* xr = (c & 1) ? Xg1 : Xg0;
    float* xw = (c & 1) ? Xg0 : Xg1;
    int gM = (c + 1 < nchunks) ? Tc * BBATCH : 0;
    const float* Xn = X + (size_t)(c + 1) * Tc * BBATCH * IDIM;
    k_fused<<<dim3(256), dim3(512), 0, stream>>>(
        xr, xw, WhT, WxT, Xn, bias, hb0, hb1, S, out, flags,
        c * Tc, Tc, /*nrec=*/NREC, gM);
  }
}